// Round 5
// baseline (1122.873 us; speedup 1.0000x reference)
//
#include <hip/hip_runtime.h>
#include <hip/hip_bf16.h>

typedef __bf16 bf16;
typedef __bf16 bf16x8 __attribute__((ext_vector_type(8)));
typedef __bf16 bf16x4 __attribute__((ext_vector_type(4)));
typedef float  f32x4  __attribute__((ext_vector_type(4)));

#define S_LEN   6400
#define NBATCH  2
#define DMODEL  2048
#define NHEADS  16
#define DHEAD   128
#define NSEG    50
#define SEGLEN  128
#define MROWS   (S_LEN*NBATCH)     // 12800
#define QKV_N   (3*DMODEL)         // 6144

static __device__ __forceinline__ f32x4 mfma16x16x32(bf16x8 a, bf16x8 b, f32x4 c) {
    return __builtin_amdgcn_mfma_f32_16x16x32_bf16(a, b, c, 0, 0, 0);
}
static __device__ __forceinline__ void gload_lds16(const bf16* g, bf16* l) {
    __builtin_amdgcn_global_load_lds(
        (const __attribute__((address_space(1))) void*)g,
        (__attribute__((address_space(3))) void*)l, 16, 0, 0);
}
static __device__ __forceinline__ float elu1(float x) {
    return x > 0.f ? x + 1.f : __expf(x);
}

// ---------------------------------------------------------------------------
// fp32 -> bf16 elementwise
// ---------------------------------------------------------------------------
__global__ void f32_to_bf16_vec(const float* __restrict__ in, bf16* __restrict__ out, int n8)
{
    const int stride = gridDim.x * blockDim.x;
    for (int i = blockIdx.x * blockDim.x + threadIdx.x; i < n8; i += stride) {
        const float4* p = (const float4*)(in + (size_t)i * 8);
        float4 v0 = p[0], v1 = p[1];
        bf16x8 o;
        o[0]=(bf16)v0.x; o[1]=(bf16)v0.y; o[2]=(bf16)v0.z; o[3]=(bf16)v0.w;
        o[4]=(bf16)v1.x; o[5]=(bf16)v1.y; o[6]=(bf16)v1.z; o[7]=(bf16)v1.w;
        *(bf16x8*)(out + (size_t)i * 8) = o;
    }
}

// ---------------------------------------------------------------------------
// W[K][N] fp32 -> WT[N][K] bf16
// ---------------------------------------------------------------------------
__global__ void transpose_f32_to_bf16(const float* __restrict__ W, bf16* __restrict__ WT,
                                      int K, int N)
{
    __shared__ float tile[32][33];
    const int n0 = blockIdx.x * 32, k0 = blockIdx.y * 32;
    const int tx = threadIdx.x & 31, ty = threadIdx.x >> 5;
    #pragma unroll
    for (int i = 0; i < 4; i++) {
        int kk = ty + i * 8;
        tile[kk][tx] = W[(size_t)(k0 + kk) * N + n0 + tx];
    }
    __syncthreads();
    #pragma unroll
    for (int i = 0; i < 4; i++) {
        int nn = ty + i * 8;
        WT[(size_t)(n0 + nn) * K + k0 + tx] = (bf16)tile[tx][nn];
    }
}

// ---------------------------------------------------------------------------
// m97-structure GEMM, BK=64: C[M,N] = A[M,2048] x BT[N,2048]^T (bf16 in).
// 128x128 tile, 4 waves (2x2), global_load_lds width-16 staging (linear LDS),
// 2-barrier K-loop (16 iters), 32 MFMA/iter.
// ---------------------------------------------------------------------------
template<bool CBF16>
__global__ __launch_bounds__(256) void gemm_bt(const bf16* __restrict__ A,
                                               const bf16* __restrict__ BT,
                                               void* __restrict__ Cptr, int Ndim)
{
    constexpr int K = DMODEL;
    __shared__ bf16 a_sm[128*64];
    __shared__ bf16 b_sm[128*64];
    const int tid = threadIdx.x;
    const int l = tid & 63, wid = tid >> 6;
    const int wr = wid >> 1, wc = wid & 1;
    const int brow = blockIdx.x * 128, bcol = blockIdx.y * 128;
    const int l15 = l & 15, lk = (l >> 4) * 8, r0 = (l >> 4) * 4;

    // staging: 4 issues per matrix; issue i covers rows i*32..i*32+31
    const int s_row = tid >> 3;          // 0..31
    const int s_col = (tid & 7) << 3;    // 0..56
    const bf16* Abase = A  + (size_t)(brow + s_row) * K + s_col;
    const bf16* Bbase = BT + (size_t)(bcol + s_row) * K + s_col;

    f32x4 acc[4][4];
    #pragma unroll
    for (int i = 0; i < 4; i++)
        #pragma unroll
        for (int j = 0; j < 4; j++)
            #pragma unroll
            for (int e = 0; e < 4; e++) acc[i][j][e] = 0.0f;

    for (int kt = 0; kt < K / 64; ++kt) {
        const int k0 = kt * 64;
        #pragma unroll
        for (int i = 0; i < 4; i++) {
            gload_lds16(Abase + (size_t)(i * 32) * K + k0, &a_sm[i * 2048 + tid * 8]);
            gload_lds16(Bbase + (size_t)(i * 32) * K + k0, &b_sm[i * 2048 + tid * 8]);
        }
        __syncthreads();   // drains vmcnt -> tiles resident

        bf16x8 af[4][2], bfr[4][2];
        #pragma unroll
        for (int mi = 0; mi < 4; mi++)
            #pragma unroll
            for (int ks = 0; ks < 2; ks++)
                af[mi][ks] = *(const bf16x8*)&a_sm[(wr*64 + mi*16 + l15)*64 + ks*32 + lk];
        #pragma unroll
        for (int ni = 0; ni < 4; ni++)
            #pragma unroll
            for (int ks = 0; ks < 2; ks++)
                bfr[ni][ks] = *(const bf16x8*)&b_sm[(wc*64 + ni*16 + l15)*64 + ks*32 + lk];
        #pragma unroll
        for (int mi = 0; mi < 4; mi++)
            #pragma unroll
            for (int ni = 0; ni < 4; ni++) {
                acc[mi][ni] = mfma16x16x32(af[mi][0], bfr[ni][0], acc[mi][ni]);
                acc[mi][ni] = mfma16x16x32(af[mi][1], bfr[ni][1], acc[mi][ni]);
            }
        __syncthreads();   // compute done before next-tile overwrite
    }

    #pragma unroll
    for (int mi = 0; mi < 4; mi++)
        #pragma unroll
        for (int ni = 0; ni < 4; ni++) {
            int row = brow + wr*64 + mi*16 + r0;
            int col = bcol + wc*64 + ni*16 + l15;
            #pragma unroll
            for (int j = 0; j < 4; j++) {
                float v = acc[mi][ni][j];
                if (CBF16) ((bf16*)Cptr)[(size_t)(row + j) * Ndim + col] = (bf16)v;
                else       ((float*)Cptr)[(size_t)(row + j) * Ndim + col] = v;
            }
        }
}

// ---------------------------------------------------------------------------
// Local causal attention; writes lob = (1-g)*local_out.
// ---------------------------------------------------------------------------
__global__ void attn_local(const bf16* __restrict__ qkv,
                           bf16* __restrict__ lob,
                           const float* __restrict__ bal)
{
    __shared__ bf16 qp_sm[128*136];
    __shared__ bf16 k_sm [128*136];
    __shared__ bf16 vT_sm[128*136];
    const int bid = blockIdx.x;
    const int h = bid & 15, b = (bid >> 4) & 1, n = bid >> 5;
    const int tid = threadIdx.x, l = tid & 63, w = tid >> 6;
    const int l15 = l & 15, lk = (l >> 4) * 8, r0 = (l >> 4) * 4;
    const float g  = 1.f / (1.f + __expf(-bal[h]));
    const float w1 = 1.f - g;

    {
        const int srow = tid >> 1, off = (tid & 1) << 6;
        const size_t gb = ((size_t)(n*SEGLEN + srow)*NBATCH + b)*QKV_N + h*DHEAD + off;
        const bf16* qsrc = qkv + gb;
        const bf16* ksrc = qkv + gb + DMODEL;
        const bf16* vsrc = qkv + gb + 2*DMODEL;
        #pragma unroll
        for (int j = 0; j < 64; j += 8) {
            *(bf16x8*)&qp_sm[srow*136 + off + j] = *(const bf16x8*)(qsrc + j);
            *(bf16x8*)&k_sm [srow*136 + off + j] = *(const bf16x8*)(ksrc + j);
        }
        #pragma unroll
        for (int j = 0; j < 64; j++) vT_sm[(off + j)*136 + srow] = vsrc[j];
    }
    __syncthreads();

    f32x4 sc[2][8];
    for (int mi = 0; mi < 2; mi++) for (int ni = 0; ni < 8; ni++)
        for (int e = 0; e < 4; e++) sc[mi][ni][e] = 0.f;
    #pragma unroll
    for (int ks = 0; ks < 4; ks++) {
        const int ko = ks*32 + lk;
        bf16x8 aq[2], bk[8];
        #pragma unroll
        for (int mi = 0; mi < 2; mi++)
            aq[mi] = *(const bf16x8*)&qp_sm[(w*32 + mi*16 + l15)*136 + ko];
        #pragma unroll
        for (int ni = 0; ni < 8; ni++)
            bk[ni] = *(const bf16x8*)&k_sm[(ni*16 + l15)*136 + ko];
        #pragma unroll
        for (int mi = 0; mi < 2; mi++)
            #pragma unroll
            for (int ni = 0; ni < 8; ni++)
                sc[mi][ni] = mfma16x16x32(aq[mi], bk[ni], sc[mi][ni]);
    }
    __syncthreads();

    const float scale = 0.088388347648318433f;
    #pragma unroll
    for (int mi = 0; mi < 2; mi++) {
        #pragma unroll
        for (int j = 0; j < 4; j++) {
            const int R = w*32 + mi*16 + r0 + j;
            float v[8]; float mx = -1e30f;
            #pragma unroll
            for (int ni = 0; ni < 8; ni++) {
                float x = sc[mi][ni][j] * scale;
                if (ni*16 + l15 > R) x = -1e9f;
                v[ni] = x; mx = fmaxf(mx, x);
            }
            #pragma unroll
            for (int d = 1; d < 16; d <<= 1) mx = fmaxf(mx, __shfl_xor(mx, d));
            float sum = 0.f;
            #pragma unroll
            for (int ni = 0; ni < 8; ni++) { v[ni] = __expf(v[ni] - mx); sum += v[ni]; }
            #pragma unroll
            for (int d = 1; d < 16; d <<= 1) sum += __shfl_xor(sum, d);
            const float inv = 1.f / sum;
            #pragma unroll
            for (int ni = 0; ni < 8; ni++)
                qp_sm[R*136 + ni*16 + l15] = (bf16)(v[ni] * inv);
        }
    }
    __syncthreads();

    f32x4 o[2][8];
    for (int mi = 0; mi < 2; mi++) for (int ni = 0; ni < 8; ni++)
        for (int e = 0; e < 4; e++) o[mi][ni][e] = 0.f;
    #pragma unroll
    for (int ks = 0; ks < 4; ks++) {
        const int ko = ks*32 + lk;
        bf16x8 ap[2], bv[8];
        #pragma unroll
        for (int mi = 0; mi < 2; mi++)
            ap[mi] = *(const bf16x8*)&qp_sm[(w*32 + mi*16 + l15)*136 + ko];
        #pragma unroll
        for (int ni = 0; ni < 8; ni++)
            bv[ni] = *(const bf16x8*)&vT_sm[(ni*16 + l15)*136 + ko];
        #pragma unroll
        for (int mi = 0; mi < 2; mi++)
            #pragma unroll
            for (int ni = 0; ni < 8; ni++)
                o[mi][ni] = mfma16x16x32(ap[mi], bv[ni], o[mi][ni]);
    }

    #pragma unroll
    for (int mi = 0; mi < 2; mi++)
        #pragma unroll
        for (int ni = 0; ni < 8; ni++) {
            const int R = w*32 + mi*16 + r0;
            const int c = ni*16 + l15;
            #pragma unroll
            for (int j = 0; j < 4; j++)
                lob[((size_t)(n*SEGLEN + R + j)*NBATCH + b)*DMODEL + h*DHEAD + c] =
                    (bf16)(w1 * o[mi][ni][j]);
        }
}

// ---------------------------------------------------------------------------
// prep_ksum: ksum[bh,n,dk] = sum_s elu1(k). grid (50,32), 256 threads.
// ---------------------------------------------------------------------------
__global__ void prep_ksum(const bf16* __restrict__ qkv, float* __restrict__ ksum)
{
    __shared__ bf16 sk_sm[128*136];
    const int n = blockIdx.x, bh = blockIdx.y;
    const int b = bh >> 4, h = bh & 15;
    const int tid = threadIdx.x;
    const int s = tid >> 1, off = (tid & 1) << 6;
    const size_t kbase = ((size_t)(n*SEGLEN + s)*NBATCH + b)*QKV_N + DMODEL + h*DHEAD + off;
    #pragma unroll
    for (int j = 0; j < 64; j += 8) {
        bf16x8 kv = *(const bf16x8*)(qkv + kbase + j);
        bf16x8 skv;
        #pragma unroll
        for (int e = 0; e < 8; e++) skv[e] = (bf16)elu1((float)kv[e]);
        *(bf16x8*)&sk_sm[s*136 + off + j] = skv;
    }
    __syncthreads();
    if (tid < 128) {
        float a = 0.f;
        for (int ss = 0; ss < 128; ss++) a += (float)sk_sm[ss*136 + tid];
        ksum[((size_t)bh*NSEG + n)*128 + tid] = a;
    }
}

// ---------------------------------------------------------------------------
// prefix_norm: normprev[bh,n,dk] = sum_{m<n} ksum[bh,m,dk]. grid 32 x 128thr.
// ---------------------------------------------------------------------------
__global__ void prefix_norm(const float* __restrict__ ksum, float* __restrict__ normprev)
{
    const int bh = blockIdx.x, dk = threadIdx.x;
    float a = 0.f;
    for (int n = 0; n < NSEG; n++) {
        const size_t i = ((size_t)bh*NSEG + n)*128 + dk;
        normprev[i] = a;
        a += ksum[i];
    }
}

// ---------------------------------------------------------------------------
// prep_U: U_n = skT @ v (bf16 out); denq_n[s] = dot(sq[s], norm_{n-1});
// invk_n[s] = 1/dot(sk[s], norm_{n-1}) (n>0). grid (50,32), 256 thr = 4 waves.
// ---------------------------------------------------------------------------
__global__ __launch_bounds__(256) void prep_U(const bf16* __restrict__ qkv,
                                              const float* __restrict__ normprev,
                                              bf16* __restrict__ Ub,
                                              float* __restrict__ denqb,
                                              float* __restrict__ invkb)
{
    __shared__ bf16  skT[128*136];
    __shared__ bf16  vT [128*136];
    __shared__ float norm_sm[128];
    __shared__ float partq[256], partk[256];

    const int n = blockIdx.x, bh = blockIdx.y;
    const int b = bh >> 4, h = bh & 15;
    const size_t seg = (size_t)bh*NSEG + n;
    const int tid = threadIdx.x, l = tid & 63, w = tid >> 6;
    const int wr = w >> 1, wc = w & 1;
    const int l15 = l & 15, lk = (l >> 4) * 8, r0 = (l >> 4) * 4;
    const int s = tid >> 1, off = (tid & 1) << 6;

    const size_t rowb = ((size_t)(n*SEGLEN + s)*NBATCH + b)*QKV_N + h*DHEAD + off;
    { // stage skT, vT (transposed)
        #pragma unroll
        for (int j = 0; j < 64; j += 8) {
            bf16x8 kv = *(const bf16x8*)(qkv + rowb + DMODEL + j);
            bf16x8 vv = *(const bf16x8*)(qkv + rowb + 2*DMODEL + j);
            #pragma unroll
            for (int e = 0; e < 8; e++) {
                skT[(off + j + e)*136 + s] = (bf16)elu1((float)kv[e]);
                vT [(off + j + e)*136 + s] = vv[e];
            }
        }
    }
    if (tid < 128) norm_sm[tid] = (n > 0) ? normprev[seg*128 + tid] : 0.f;
    __syncthreads();

    if (n > 0) {
        float aq = 0.f;
        #pragma unroll
        for (int j = 0; j < 64; j += 8) {
            bf16x8 qa = *(const bf16x8*)(qkv + rowb + j);
            #pragma unroll
            for (int e = 0; e < 8; e++) aq += elu1((float)qa[e]) * norm_sm[off + j + e];
        }
        float ak = 0.f;
        for (int d = off; d < off + 64; d++) ak += (float)skT[d*136 + s] * norm_sm[d];
        partq[tid] = aq; partk[tid] = ak;
    }
    __syncthreads();
    if (n > 0 && tid < 128) {
        denqb[seg*128 + tid] = partq[tid*2] + partq[tid*2 + 1];
        invkb[seg*128 + tid] = 1.f / (partk[tid*2] + partk[tid*2 + 1]);
    }

    // ---- U = skT @ v   (128x128, 2x2 waves, 4x4 frags)
    f32x4 ua[4][4];
    for (int mi = 0; mi < 4; mi++) for (int ni = 0; ni < 4; ni++)
        for (int e = 0; e < 4; e++) ua[mi][ni][e] = 0.f;
    #pragma unroll
    for (int ks = 0; ks < 4; ks++) {
        const int ko = ks*32 + lk;
        bf16x8 af[4], bv[4];
        #pragma unroll
        for (int mi = 0; mi < 4; mi++)
            af[mi] = *(const bf16x8*)&skT[(wr*64 + mi*16 + l15)*136 + ko];
        #pragma unroll
        for (int ni = 0; ni < 4; ni++)
            bv[ni] = *(const bf16x8*)&vT[(wc*64 + ni*16 + l15)*136 + ko];
        #pragma unroll
        for (int mi = 0; mi < 4; mi++)
            #pragma unroll
            for (int ni = 0; ni < 4; ni++)
                ua[mi][ni] = mfma16x16x32(af[mi], bv[ni], ua[mi][ni]);
    }
    #pragma unroll
    for (int mi = 0; mi < 4; mi++)
        #pragma unroll
        for (int ni = 0; ni < 4; ni++) {
            const int row = wr*64 + mi*16 + r0, col = wc*64 + ni*16 + l15;
            #pragma unroll
            for (int j = 0; j < 4; j++)
                Ub[(seg << 14) + (size_t)(row + j)*128 + col] = (bf16)ua[mi][ni][j];
        }
}

// ---------------------------------------------------------------------------
// scan2: mem_n = mem_{n-1} - skT@((sk@mem_{n-1})/denk) + U_n ;
//        retr  = (sq@mem_{n-1})/denq ; lob += g*retr.
// Grid 256 = bh*8 + dq (dv-EIGHTH, 16 dv cols/block -> full chip). 256 thr =
// 4 waves (32 s/dk rows each). memT[16][136] bf16 LDS; f32 master in regs;
// q/k loaded direct global (elu on the fly), double-buffered.
// ---------------------------------------------------------------------------
__global__ __launch_bounds__(256, 1) void scan2(const bf16* __restrict__ qkv,
                                                const bf16* __restrict__ Ub,
                                                const float* __restrict__ denqb,
                                                const float* __restrict__ invkb,
                                                bf16* __restrict__ lob,
                                                const float* __restrict__ bal)
{
    __shared__ bf16 memT[16*136];
    __shared__ bf16 skT [128*136];
    __shared__ bf16 yT  [16*136];
    const int bid = blockIdx.x;
    const int bh = bid >> 3, dq = bid & 7;
    const int b = bh >> 4, h = bh & 15;
    const int tid = threadIdx.x, l = tid & 63, w = tid >> 6;
    const int l15 = l & 15, lk = (l >> 4) * 8, r0 = (l >> 4) * 4;
    const float g = 1.f / (1.f + __expf(-bal[h]));
    const size_t segb = (size_t)bh * NSEG;
    const int cdv = dq*16 + l15;              // global dv column

    // init: mast = U0, memT = bf16(mast)   (memT[dv local][dk], stride 136)
    float mast[2][4];
    #pragma unroll
    for (int mi = 0; mi < 2; mi++)
        #pragma unroll
        for (int j = 0; j < 4; j++) {
            const int row = w*32 + mi*16 + r0 + j;
            mast[mi][j] = (float)Ub[(segb << 14) + (size_t)row*128 + cdv];
            memT[l15*136 + row] = (bf16)mast[mi][j];
        }
    __syncthreads();

    bf16x8 qA[8], kA[8], qB[8], kB[8];   // raw q/k frags [mi*4+ks]

    auto loadraw = [&](int n2, bf16x8* qr, bf16x8* kr) {
        #pragma unroll
        for (int mi = 0; mi < 2; mi++)
            #pragma unroll
            for (int ks = 0; ks < 4; ks++) {
                const size_t base =
                    ((size_t)(n2*SEGLEN + w*32 + mi*16 + l15)*NBATCH + b)*QKV_N
                    + h*DHEAD + ks*32 + lk;
                qr[mi*4 + ks] = *(const bf16x8*)(qkv + base);
                kr[mi*4 + ks] = *(const bf16x8*)(qkv + base + DMODEL);
            }
    };

    auto step = [&](int n, bf16x8* curq, bf16x8* curk, bf16x8* nxtq, bf16x8* nxtk) {
        // epilogue scalars issued early
        float uval[2][4], lv[2][4], dqv[2][4], ivk[2][4];
        #pragma unroll
        for (int mi = 0; mi < 2; mi++)
            #pragma unroll
            for (int j = 0; j < 4; j++) {
                const int sx = w*32 + mi*16 + r0 + j;
                dqv[mi][j] = denqb[(segb + n)*128 + sx];
                ivk[mi][j] = invkb[(segb + n)*128 + sx];
                uval[mi][j] = (float)Ub[((segb + n) << 14) + (size_t)sx*128 + cdv];
                lv[mi][j] = (float)lob[((size_t)(n*SEGLEN + sx)*NBATCH + b)*DMODEL
                                       + h*DHEAD + cdv];
            }
        // elu
        bf16x8 sqf[8], skf[8];
        #pragma unroll
        for (int f = 0; f < 8; f++) {
            bf16x8 qv = curq[f], kv = curk[f], sq_, sk_;
            #pragma unroll
            for (int e = 0; e < 8; e++) {
                sq_[e] = (bf16)elu1((float)qv[e]);
                sk_[e] = (bf16)elu1((float)kv[e]);
            }
            sqf[f] = sq_; skf[f] = sk_;
        }
        // skT writes (transposed)
        #pragma unroll
        for (int mi = 0; mi < 2; mi++)
            #pragma unroll
            for (int ks = 0; ks < 4; ks++)
                #pragma unroll
                for (int e = 0; e < 8; e++)
                    skT[(ks*32 + lk + e)*136 + w*32 + mi*16 + l15] = skf[mi*4 + ks][e];
        // racc = sq@mem, yacc = sk@mem  (B-frag from memT, single 16-col frag)
        f32x4 racc[2], yacc[2];
        #pragma unroll
        for (int mi = 0; mi < 2; mi++)
            #pragma unroll
            for (int e = 0; e < 4; e++) { racc[mi][e] = 0.f; yacc[mi][e] = 0.f; }
        #pragma unroll
        for (int ks = 0; ks < 4; ks++) {
            bf16x8 bm = *(const bf16x8*)&memT[l15*136 + ks*32 + lk];
            #pragma unroll
            for (int mi = 0; mi < 2; mi++) {
                racc[mi] = mfma16x16x32(sqf[mi*4 + ks], bm, racc[mi]);
                yacc[mi] = mfma16x16x32(skf[mi*4 + ks], bm, yacc[mi]);
            }
        }
        if (n < NSEG - 1) loadraw(n + 1, nxtq, nxtk);
        // y' = yacc/denk -> yT (transposed)
        #pragma unroll
        for (int mi = 0; mi < 2; mi++)
            #pragma unroll
            for (int j = 0; j < 4; j++)
                yT[l15*136 + w*32 + mi*16 + r0 + j] = (bf16)(yacc[mi][j] * ivk[mi][j]);
        __syncthreads();
        // zacc = skT @ y'
        f32x4 zacc[2];
        #pragma unroll
        for (int mi = 0; mi < 2; mi++)
            #pragma unroll
            for (int e = 0; e < 4; e++) zacc[mi][e] = 0.f;
        #pragma unroll
        for (int ks = 0; ks < 4; ks++) {
            bf16x8 bz = *(const bf16x8*)&yT[l15*136 + ks*32 + lk];
            #pragma unroll
            for (int mi = 0; mi < 2; mi++) {
                bf16x8 az = *(const bf16x8*)&skT[(w*32 + mi*16 + l15)*136 + ks*32 + lk];
                zacc[mi] = mfma16x16x32(az, bz, zacc[mi]);
            }
        }
        // epilogue: retr out, master update, memT refresh
        #pragma unroll
        for (int mi = 0; mi < 2; mi++)
            #pragma unroll
            for (int j = 0; j < 4; j++) {
                const int sx = w*32 + mi*16 + r0 + j;
                const float rv = racc[mi][j] / dqv[mi][j];
                lob[((size_t)(n*SEGLEN + sx)*NBATCH + b)*DMODEL + h*DHEAD + cdv] =
                    (bf16)(lv[mi][j] + g * rv);
                mast[mi][j] += uval[mi][j] - zacc[mi][j];
                memT[l15*136 + sx] = (bf16)mast[mi][j];
            }
        __syncthreads();
    };

    loadraw(1, qA, kA);
    for (int n = 1; n < NSEG; n += 2) {
        step(n, qA, kA, qB, kB);
        if (n + 1 < NSEG) step(n + 1, qB, kB, qA, kA);
    }
}

// ---------------------------------------------------------------------------
// Workspace layout (max 295,698,432 B, proven-safe):
//   [0)            qkvb  157,286,400
//   [157,286,400)  lob    52,428,800
//   [209,715,200)  woT     8,388,608
//   [218,103,808)  abf    52,428,800   -> reused as Ub (bf16) after QKV GEMM
//   [270,532,608)  wqkvT  25,165,824   -> reused as ksum/normp/denqb/invkb
// ---------------------------------------------------------------------------
extern "C" void kernel_launch(void* const* d_in, const int* in_sizes, int n_in,
                              void* d_out, int out_size, void* d_ws, size_t ws_size,
                              hipStream_t stream)
{
    (void)in_sizes; (void)n_in; (void)out_size; (void)ws_size;
    const float* hidden = (const float*)d_in[0];
    const float* w_qkv  = (const float*)d_in[2];
    const float* w_o    = (const float*)d_in[3];
    const float* bal    = (const float*)d_in[4];

    char* ws = (char*)d_ws;
    bf16*  qkvb  = (bf16*)ws;
    bf16*  lob   = (bf16*)(ws + 157286400);
    bf16*  woT   = (bf16*)(ws + 209715200);
    bf16*  abf   = (bf16*)(ws + 218103808);
    bf16*  Ub    = abf;                       // overlay: abf dead after QKV GEMM
    bf16*  wqkvT = (bf16*)(ws + 270532608);
    float* ksum  = (float*)(ws + 270532608);  // overlay: wqkvT dead after QKV GEMM
    float* normp = (float*)(ws + 271351808);
    float* denqb = (float*)(ws + 272171008);
    float* invkb = (float*)(ws + 272990208);

    dim3 blk(256);
    f32_to_bf16_vec<<<2048, blk, 0, stream>>>(hidden, abf, MROWS*DMODEL/8);
    transpose_f32_to_bf16<<<dim3(QKV_N/32, DMODEL/32), blk, 0, stream>>>(w_qkv, wqkvT, DMODEL, QKV_N);
    transpose_f32_to_bf16<<<dim3(DMODEL/32, DMODEL/32), blk, 0, stream>>>(w_o, woT, DMODEL, DMODEL);

    gemm_bt<true><<<dim3(MROWS/128, QKV_N/128), blk, 0, stream>>>(abf, wqkvT, qkvb, QKV_N);

    prep_ksum<<<dim3(NSEG, 32), blk, 0, stream>>>(qkvb, ksum);
    prefix_norm<<<32, 128, 0, stream>>>(ksum, normp);
    prep_U<<<dim3(NSEG, 32), blk, 0, stream>>>(qkvb, normp, Ub, denqb, invkb);

    attn_local<<<dim3(NSEG*NBATCH*NHEADS), blk, 0, stream>>>(qkvb, lob, bal);
    scan2<<<256, blk, 0, stream>>>(qkvb, Ub, denqb, invkb, lob, bal);

    gemm_bt<false><<<dim3(MROWS/128, DMODEL/128), blk, 0, stream>>>(lob, woT, d_out, DMODEL);
}

// Round 6
// 942.282 us; speedup vs baseline: 1.1917x; 1.1917x over previous
//
#include <hip/hip_runtime.h>
#include <hip/hip_bf16.h>

typedef __bf16 bf16;
typedef __bf16 bf16x8 __attribute__((ext_vector_type(8)));
typedef __bf16 bf16x4 __attribute__((ext_vector_type(4)));
typedef float  f32x4  __attribute__((ext_vector_type(4)));

#define S_LEN   6400
#define NBATCH  2
#define DMODEL  2048
#define NHEADS  16
#define DHEAD   128
#define NSEG    50
#define SEGLEN  128
#define MROWS   (S_LEN*NBATCH)     // 12800
#define QKV_N   (3*DMODEL)         // 6144

static __device__ __forceinline__ f32x4 mfma16x16x32(bf16x8 a, bf16x8 b, f32x4 c) {
    return __builtin_amdgcn_mfma_f32_16x16x32_bf16(a, b, c, 0, 0, 0);
}
static __device__ __forceinline__ void gload_lds16(const bf16* g, bf16* l) {
    __builtin_amdgcn_global_load_lds(
        (const __attribute__((address_space(1))) void*)g,
        (__attribute__((address_space(3))) void*)l, 16, 0, 0);
}
static __device__ __forceinline__ float elu1(float x) {
    return x > 0.f ? x + 1.f : __expf(x);
}

// ---------------------------------------------------------------------------
// fp32 -> bf16 elementwise
// ---------------------------------------------------------------------------
__global__ void f32_to_bf16_vec(const float* __restrict__ in, bf16* __restrict__ out, int n8)
{
    const int stride = gridDim.x * blockDim.x;
    for (int i = blockIdx.x * blockDim.x + threadIdx.x; i < n8; i += stride) {
        const float4* p = (const float4*)(in + (size_t)i * 8);
        float4 v0 = p[0], v1 = p[1];
        bf16x8 o;
        o[0]=(bf16)v0.x; o[1]=(bf16)v0.y; o[2]=(bf16)v0.z; o[3]=(bf16)v0.w;
        o[4]=(bf16)v1.x; o[5]=(bf16)v1.y; o[6]=(bf16)v1.z; o[7]=(bf16)v1.w;
        *(bf16x8*)(out + (size_t)i * 8) = o;
    }
}

// ---------------------------------------------------------------------------
// W[K][N] fp32 -> WT[N][K] bf16
// ---------------------------------------------------------------------------
__global__ void transpose_f32_to_bf16(const float* __restrict__ W, bf16* __restrict__ WT,
                                      int K, int N)
{
    __shared__ float tile[32][33];
    const int n0 = blockIdx.x * 32, k0 = blockIdx.y * 32;
    const int tx = threadIdx.x & 31, ty = threadIdx.x >> 5;
    #pragma unroll
    for (int i = 0; i < 4; i++) {
        int kk = ty + i * 8;
        tile[kk][tx] = W[(size_t)(k0 + kk) * N + n0 + tx];
    }
    __syncthreads();
    #pragma unroll
    for (int i = 0; i < 4; i++) {
        int nn = ty + i * 8;
        WT[(size_t)(n0 + nn) * K + k0 + tx] = (bf16)tile[tx][nn];
    }
}

// ---------------------------------------------------------------------------
// gemm256: C[M,N] = A[M,2048] x BT[N,2048]^T, 256x256 tile, BK=32, 512 thr =
// 8 waves (2M x 4N), per-wave 128x64 output (acc[8][4]).
// Deep pipeline: global_load_lds double-buffer, counted s_waitcnt vmcnt(4)
// (never 0 mid-loop), raw s_barrier; tile t in buf[t&1], staged at t-2.
// LDS swizzle: paired-row layout, slot(0..7) = ((row&1)*4 + kchunk) ^
// ((row>>1)&7) -> ds_read_b128 2-way conflict (free). Staged via pre-swizzled
// GLOBAL source + linear LDS dest (rule #21).
// ---------------------------------------------------------------------------
template<bool CBF16>
__global__ __launch_bounds__(512, 2) void gemm256(const bf16* __restrict__ A,
                                                  const bf16* __restrict__ BT,
                                                  void* __restrict__ Cptr, int Ndim)
{
    constexpr int K = DMODEL;
    constexpr int NT = K / 32;          // 64 K-tiles
    __shared__ __align__(16) bf16 a_sm[2][256*32];
    __shared__ __align__(16) bf16 b_sm[2][256*32];

    const int tid = threadIdx.x;
    const int l = tid & 63, wid = tid >> 6;
    const int wm = wid >> 2, wn = wid & 3;          // 2 x 4 waves
    const int brow = blockIdx.x * 256, bcol = blockIdx.y * 256;
    const int l15 = l & 15, lg = l >> 4;            // lg = k-chunk 0..3

    // ---- staging map (pre-swizzled global source, linear LDS dest)
    const int st_mr  = tid >> 3;                    // macrorow 0..63 per issue
    const int st_s0  = (tid & 7) ^ (st_mr & 7);     // unswizzled slot
    const int st_row = 2 * st_mr + (st_s0 >> 2);    // source row 0..127
    const int st_col = (st_s0 & 3) << 3;            // source k-chunk elems
    const bf16* Asrc = A  + (size_t)(brow + st_row) * K + st_col;
    const bf16* Bsrc = BT + (size_t)(bcol + st_row) * K + st_col;

    // ---- fragment LDS element offsets (swizzled read)
    int aoff[8], boff[4];
    #pragma unroll
    for (int mi = 0; mi < 8; mi++) {
        const int r = wm*128 + mi*16 + l15, mr = r >> 1;
        aoff[mi] = mr*64 + ((((( r & 1) << 2) | lg) ^ (mr & 7)) << 3);
    }
    #pragma unroll
    for (int ni = 0; ni < 4; ni++) {
        const int r = wn*64 + ni*16 + l15, mr = r >> 1;
        boff[ni] = mr*64 + ((((( r & 1) << 2) | lg) ^ (mr & 7)) << 3);
    }

    f32x4 acc[8][4];
    #pragma unroll
    for (int mi = 0; mi < 8; mi++)
        #pragma unroll
        for (int ni = 0; ni < 4; ni++)
            #pragma unroll
            for (int e = 0; e < 4; e++) acc[mi][ni][e] = 0.f;

    auto STAGE = [&](int buf, int kt2) {
        const int k0 = kt2 * 32;
        #pragma unroll
        for (int i = 0; i < 2; i++) {
            gload_lds16(Asrc + (size_t)(i*128) * K + k0, &a_sm[buf][i*4096 + tid*8]);
            gload_lds16(Bsrc + (size_t)(i*128) * K + k0, &b_sm[buf][i*4096 + tid*8]);
        }
    };

    // ---- prologue: tiles 0,1 in flight; wait tile 0 (4 newest stay in flight)
    STAGE(0, 0);
    STAGE(1, 1);
    asm volatile("s_waitcnt vmcnt(4)" ::: "memory");
    __builtin_amdgcn_sched_barrier(0);
    __builtin_amdgcn_s_barrier();

    int cur = 0;
    for (int kt = 0; kt < NT; ++kt) {
        // ---- LDS -> regs (swizzled, conflict-free)
        bf16x8 af[8], bfr[4];
        #pragma unroll
        for (int mi = 0; mi < 8; mi++) af[mi]  = *(const bf16x8*)&a_sm[cur][aoff[mi]];
        #pragma unroll
        for (int ni = 0; ni < 4; ni++) bfr[ni] = *(const bf16x8*)&b_sm[cur][boff[ni]];
        asm volatile("s_waitcnt lgkmcnt(0)" ::: "memory");
        __builtin_amdgcn_sched_barrier(0);
        __builtin_amdgcn_s_barrier();          // buf[cur] free for overwrite

        if (kt + 2 < NT) STAGE(cur, kt + 2);   // issue before MFMA
        __builtin_amdgcn_sched_barrier(0);

        __builtin_amdgcn_s_setprio(1);
        #pragma unroll
        for (int mi = 0; mi < 8; mi++)
            #pragma unroll
            for (int ni = 0; ni < 4; ni++)
                acc[mi][ni] = mfma16x16x32(af[mi], bfr[ni], acc[mi][ni]);
        __builtin_amdgcn_s_setprio(0);

        if (kt + 2 < NT)      asm volatile("s_waitcnt vmcnt(4)" ::: "memory");
        else if (kt + 1 < NT) asm volatile("s_waitcnt vmcnt(0)" ::: "memory");
        __builtin_amdgcn_sched_barrier(0);
        __builtin_amdgcn_s_barrier();          // buf[cur^1] (tile kt+1) ready
        cur ^= 1;
    }

    // ---- epilogue: C layout row=(l>>4)*4+j, col=l&15
    #pragma unroll
    for (int mi = 0; mi < 8; mi++)
        #pragma unroll
        for (int ni = 0; ni < 4; ni++) {
            const int row = brow + wm*128 + mi*16 + lg*4;
            const int col = bcol + wn*64 + ni*16 + l15;
            #pragma unroll
            for (int j = 0; j < 4; j++) {
                float v = acc[mi][ni][j];
                if (CBF16) ((bf16*)Cptr)[(size_t)(row + j) * Ndim + col] = (bf16)v;
                else       ((float*)Cptr)[(size_t)(row + j) * Ndim + col] = v;
            }
        }
}

// ---------------------------------------------------------------------------
// Local causal attention; writes lob = (1-g)*local_out.
// ---------------------------------------------------------------------------
__global__ void attn_local(const bf16* __restrict__ qkv,
                           bf16* __restrict__ lob,
                           const float* __restrict__ bal)
{
    __shared__ bf16 qp_sm[128*136];
    __shared__ bf16 k_sm [128*136];
    __shared__ bf16 vT_sm[128*136];
    const int bid = blockIdx.x;
    const int h = bid & 15, b = (bid >> 4) & 1, n = bid >> 5;
    const int tid = threadIdx.x, l = tid & 63, w = tid >> 6;
    const int l15 = l & 15, lk = (l >> 4) * 8, r0 = (l >> 4) * 4;
    const float g  = 1.f / (1.f + __expf(-bal[h]));
    const float w1 = 1.f - g;

    {
        const int srow = tid >> 1, off = (tid & 1) << 6;
        const size_t gb = ((size_t)(n*SEGLEN + srow)*NBATCH + b)*QKV_N + h*DHEAD + off;
        const bf16* qsrc = qkv + gb;
        const bf16* ksrc = qkv + gb + DMODEL;
        const bf16* vsrc = qkv + gb + 2*DMODEL;
        #pragma unroll
        for (int j = 0; j < 64; j += 8) {
            *(bf16x8*)&qp_sm[srow*136 + off + j] = *(const bf16x8*)(qsrc + j);
            *(bf16x8*)&k_sm [srow*136 + off + j] = *(const bf16x8*)(ksrc + j);
        }
        #pragma unroll
        for (int j = 0; j < 64; j++) vT_sm[(off + j)*136 + srow] = vsrc[j];
    }
    __syncthreads();

    f32x4 sc[2][8];
    for (int mi = 0; mi < 2; mi++) for (int ni = 0; ni < 8; ni++)
        for (int e = 0; e < 4; e++) sc[mi][ni][e] = 0.f;
    #pragma unroll
    for (int ks = 0; ks < 4; ks++) {
        const int ko = ks*32 + lk;
        bf16x8 aq[2], bk[8];
        #pragma unroll
        for (int mi = 0; mi < 2; mi++)
            aq[mi] = *(const bf16x8*)&qp_sm[(w*32 + mi*16 + l15)*136 + ko];
        #pragma unroll
        for (int ni = 0; ni < 8; ni++)
            bk[ni] = *(const bf16x8*)&k_sm[(ni*16 + l15)*136 + ko];
        #pragma unroll
        for (int mi = 0; mi < 2; mi++)
            #pragma unroll
            for (int ni = 0; ni < 8; ni++)
                sc[mi][ni] = mfma16x16x32(aq[mi], bk[ni], sc[mi][ni]);
    }
    __syncthreads();

    const float scale = 0.088388347648318433f;
    #pragma unroll
    for (int mi = 0; mi < 2; mi++) {
        #pragma unroll
        for (int j = 0; j < 4; j++) {
            const int R = w*32 + mi*16 + r0 + j;
            float v[8]; float mx = -1e30f;
            #pragma unroll
            for (int ni = 0; ni < 8; ni++) {
                float x = sc[mi][ni][j] * scale;
                if (ni*16 + l15 > R) x = -1e9f;
                v[ni] = x; mx = fmaxf(mx, x);
            }
            #pragma unroll
            for (int d = 1; d < 16; d <<= 1) mx = fmaxf(mx, __shfl_xor(mx, d));
            float sum = 0.f;
            #pragma unroll
            for (int ni = 0; ni < 8; ni++) { v[ni] = __expf(v[ni] - mx); sum += v[ni]; }
            #pragma unroll
            for (int d = 1; d < 16; d <<= 1) sum += __shfl_xor(sum, d);
            const float inv = 1.f / sum;
            #pragma unroll
            for (int ni = 0; ni < 8; ni++)
                qp_sm[R*136 + ni*16 + l15] = (bf16)(v[ni] * inv);
        }
    }
    __syncthreads();

    f32x4 o[2][8];
    for (int mi = 0; mi < 2; mi++) for (int ni = 0; ni < 8; ni++)
        for (int e = 0; e < 4; e++) o[mi][ni][e] = 0.f;
    #pragma unroll
    for (int ks = 0; ks < 4; ks++) {
        const int ko = ks*32 + lk;
        bf16x8 ap[2], bv[8];
        #pragma unroll
        for (int mi = 0; mi < 2; mi++)
            ap[mi] = *(const bf16x8*)&qp_sm[(w*32 + mi*16 + l15)*136 + ko];
        #pragma unroll
        for (int ni = 0; ni < 8; ni++)
            bv[ni] = *(const bf16x8*)&vT_sm[(ni*16 + l15)*136 + ko];
        #pragma unroll
        for (int mi = 0; mi < 2; mi++)
            #pragma unroll
            for (int ni = 0; ni < 8; ni++)
                o[mi][ni] = mfma16x16x32(ap[mi], bv[ni], o[mi][ni]);
    }

    #pragma unroll
    for (int mi = 0; mi < 2; mi++)
        #pragma unroll
        for (int ni = 0; ni < 8; ni++) {
            const int R = w*32 + mi*16 + r0;
            const int c = ni*16 + l15;
            #pragma unroll
            for (int j = 0; j < 4; j++)
                lob[((size_t)(n*SEGLEN + R + j)*NBATCH + b)*DMODEL + h*DHEAD + c] =
                    (bf16)(w1 * o[mi][ni][j]);
        }
}

// ---------------------------------------------------------------------------
// prep_ksum: ksum[bh,n,dk] = sum_s elu1(k). grid (50,32), 256 threads.
// ---------------------------------------------------------------------------
__global__ void prep_ksum(const bf16* __restrict__ qkv, float* __restrict__ ksum)
{
    __shared__ bf16 sk_sm[128*136];
    const int n = blockIdx.x, bh = blockIdx.y;
    const int b = bh >> 4, h = bh & 15;
    const int tid = threadIdx.x;
    const int s = tid >> 1, off = (tid & 1) << 6;
    const size_t kbase = ((size_t)(n*SEGLEN + s)*NBATCH + b)*QKV_N + DMODEL + h*DHEAD + off;
    #pragma unroll
    for (int j = 0; j < 64; j += 8) {
        bf16x8 kv = *(const bf16x8*)(qkv + kbase + j);
        bf16x8 skv;
        #pragma unroll
        for (int e = 0; e < 8; e++) skv[e] = (bf16)elu1((float)kv[e]);
        *(bf16x8*)&sk_sm[s*136 + off + j] = skv;
    }
    __syncthreads();
    if (tid < 128) {
        float a = 0.f;
        for (int ss = 0; ss < 128; ss++) a += (float)sk_sm[ss*136 + tid];
        ksum[((size_t)bh*NSEG + n)*128 + tid] = a;
    }
}

// ---------------------------------------------------------------------------
// prefix_norm: normprev[bh,n,dk] = sum_{m<n} ksum[bh,m,dk]. grid 32 x 128thr.
// ---------------------------------------------------------------------------
__global__ void prefix_norm(const float* __restrict__ ksum, float* __restrict__ normprev)
{
    const int bh = blockIdx.x, dk = threadIdx.x;
    float a = 0.f;
    for (int n = 0; n < NSEG; n++) {
        const size_t i = ((size_t)bh*NSEG + n)*128 + dk;
        normprev[i] = a;
        a += ksum[i];
    }
}

// ---------------------------------------------------------------------------
// prep_U: U_n = skT @ v (bf16 out); denq_n[s] = dot(sq[s], norm_{n-1});
// invk_n[s] = 1/dot(sk[s], norm_{n-1}) (n>0). grid (50,32), 256 thr = 4 waves.
// ---------------------------------------------------------------------------
__global__ __launch_bounds__(256) void prep_U(const bf16* __restrict__ qkv,
                                              const float* __restrict__ normprev,
                                              bf16* __restrict__ Ub,
                                              float* __restrict__ denqb,
                                              float* __restrict__ invkb)
{
    __shared__ bf16  skT[128*136];
    __shared__ bf16  vT [128*136];
    __shared__ float norm_sm[128];
    __shared__ float partq[256], partk[256];

    const int n = blockIdx.x, bh = blockIdx.y;
    const int b = bh >> 4, h = bh & 15;
    const size_t seg = (size_t)bh*NSEG + n;
    const int tid = threadIdx.x, l = tid & 63, w = tid >> 6;
    const int wr = w >> 1, wc = w & 1;
    const int l15 = l & 15, lk = (l >> 4) * 8, r0 = (l >> 4) * 4;
    const int s = tid >> 1, off = (tid & 1) << 6;

    const size_t rowb = ((size_t)(n*SEGLEN + s)*NBATCH + b)*QKV_N + h*DHEAD + off;
    {
        #pragma unroll
        for (int j = 0; j < 64; j += 8) {
            bf16x8 kv = *(const bf16x8*)(qkv + rowb + DMODEL + j);
            bf16x8 vv = *(const bf16x8*)(qkv + rowb + 2*DMODEL + j);
            #pragma unroll
            for (int e = 0; e < 8; e++) {
                skT[(off + j + e)*136 + s] = (bf16)elu1((float)kv[e]);
                vT [(off + j + e)*136 + s] = vv[e];
            }
        }
    }
    if (tid < 128) norm_sm[tid] = (n > 0) ? normprev[seg*128 + tid] : 0.f;
    __syncthreads();

    if (n > 0) {
        float aq = 0.f;
        #pragma unroll
        for (int j = 0; j < 64; j += 8) {
            bf16x8 qa = *(const bf16x8*)(qkv + rowb + j);
            #pragma unroll
            for (int e = 0; e < 8; e++) aq += elu1((float)qa[e]) * norm_sm[off + j + e];
        }
        float ak = 0.f;
        for (int d = off; d < off + 64; d++) ak += (float)skT[d*136 + s] * norm_sm[d];
        partq[tid] = aq; partk[tid] = ak;
    }
    __syncthreads();
    if (n > 0 && tid < 128) {
        denqb[seg*128 + tid] = partq[tid*2] + partq[tid*2 + 1];
        invkb[seg*128 + tid] = 1.f / (partk[tid*2] + partk[tid*2 + 1]);
    }

    f32x4 ua[4][4];
    for (int mi = 0; mi < 4; mi++) for (int ni = 0; ni < 4; ni++)
        for (int e = 0; e < 4; e++) ua[mi][ni][e] = 0.f;
    #pragma unroll
    for (int ks = 0; ks < 4; ks++) {
        const int ko = ks*32 + lk;
        bf16x8 af[4], bv[4];
        #pragma unroll
        for (int mi = 0; mi < 4; mi++)
            af[mi] = *(const bf16x8*)&skT[(wr*64 + mi*16 + l15)*136 + ko];
        #pragma unroll
        for (int ni = 0; ni < 4; ni++)
            bv[ni] = *(const bf16x8*)&vT[(wc*64 + ni*16 + l15)*136 + ko];
        #pragma unroll
        for (int mi = 0; mi < 4; mi++)
            #pragma unroll
            for (int ni = 0; ni < 4; ni++)
                ua[mi][ni] = mfma16x16x32(af[mi], bv[ni], ua[mi][ni]);
    }
    #pragma unroll
    for (int mi = 0; mi < 4; mi++)
        #pragma unroll
        for (int ni = 0; ni < 4; ni++) {
            const int row = wr*64 + mi*16 + r0, col = wc*64 + ni*16 + l15;
            #pragma unroll
            for (int j = 0; j < 4; j++)
                Ub[(seg << 14) + (size_t)(row + j)*128 + col] = (bf16)ua[mi][ni][j];
        }
}

// ---------------------------------------------------------------------------
// scan2: mem_n = mem_{n-1} - skT@((sk@mem_{n-1})/denk) + U_n ;
//        retr  = (sq@mem_{n-1})/denq ; lob += g*retr.
// Grid 256 = bh*8 + dq (dv-eighth). 256 thr = 4 waves.
// ---------------------------------------------------------------------------
__global__ __launch_bounds__(256, 1) void scan2(const bf16* __restrict__ qkv,
                                                const bf16* __restrict__ Ub,
                                                const float* __restrict__ denqb,
                                                const float* __restrict__ invkb,
                                                bf16* __restrict__ lob,
                                                const float* __restrict__ bal)
{
    __shared__ bf16 memT[16*136];
    __shared__ bf16 skT [128*136];
    __shared__ bf16 yT  [16*136];
    const int bid = blockIdx.x;
    const int bh = bid >> 3, dq = bid & 7;
    const int b = bh >> 4, h = bh & 15;
    const int tid = threadIdx.x, l = tid & 63, w = tid >> 6;
    const int l15 = l & 15, lk = (l >> 4) * 8, r0 = (l >> 4) * 4;
    const float g = 1.f / (1.f + __expf(-bal[h]));
    const size_t segb = (size_t)bh * NSEG;
    const int cdv = dq*16 + l15;

    float mast[2][4];
    #pragma unroll
    for (int mi = 0; mi < 2; mi++)
        #pragma unroll
        for (int j = 0; j < 4; j++) {
            const int row = w*32 + mi*16 + r0 + j;
            mast[mi][j] = (float)Ub[(segb << 14) + (size_t)row*128 + cdv];
            memT[l15*136 + row] = (bf16)mast[mi][j];
        }
    __syncthreads();

    bf16x8 qA[8], kA[8], qB[8], kB[8];

    auto loadraw = [&](int n2, bf16x8* qr, bf16x8* kr) {
        #pragma unroll
        for (int mi = 0; mi < 2; mi++)
            #pragma unroll
            for (int ks = 0; ks < 4; ks++) {
                const size_t base =
                    ((size_t)(n2*SEGLEN + w*32 + mi*16 + l15)*NBATCH + b)*QKV_N
                    + h*DHEAD + ks*32 + lk;
                qr[mi*4 + ks] = *(const bf16x8*)(qkv + base);
                kr[mi*4 + ks] = *(const bf16x8*)(qkv + base + DMODEL);
            }
    };

    auto step = [&](int n, bf16x8* curq, bf16x8* curk, bf16x8* nxtq, bf16x8* nxtk) {
        float uval[2][4], lv[2][4], dqv[2][4], ivk[2][4];
        #pragma unroll
        for (int mi = 0; mi < 2; mi++)
            #pragma unroll
            for (int j = 0; j < 4; j++) {
                const int sx = w*32 + mi*16 + r0 + j;
                dqv[mi][j] = denqb[(segb + n)*128 + sx];
                ivk[mi][j] = invkb[(segb + n)*128 + sx];
                uval[mi][j] = (float)Ub[((segb + n) << 14) + (size_t)sx*128 + cdv];
                lv[mi][j] = (float)lob[((size_t)(n*SEGLEN + sx)*NBATCH + b)*DMODEL
                                       + h*DHEAD + cdv];
            }
        bf16x8 sqf[8], skf[8];
        #pragma unroll
        for (int f = 0; f < 8; f++) {
            bf16x8 qv = curq[f], kv = curk[f], sq_, sk_;
            #pragma unroll
            for (int e = 0; e < 8; e++) {
                sq_[e] = (bf16)elu1((float)qv[e]);
                sk_[e] = (bf16)elu1((float)kv[e]);
            }
            sqf[f] = sq_; skf[f] = sk_;
        }
        #pragma unroll
        for (int mi = 0; mi < 2; mi++)
            #pragma unroll
            for (int ks = 0; ks < 4; ks++)
                #pragma unroll
                for (int e = 0; e < 8; e++)
                    skT[(ks*32 + lk + e)*136 + w*32 + mi*16 + l15] = skf[mi*4 + ks][e];
        f32x4 racc[2], yacc[2];
        #pragma unroll
        for (int mi = 0; mi < 2; mi++)
            #pragma unroll
            for (int e = 0; e < 4; e++) { racc[mi][e] = 0.f; yacc[mi][e] = 0.f; }
        #pragma unroll
        for (int ks = 0; ks < 4; ks++) {
            bf16x8 bm = *(const bf16x8*)&memT[l15*136 + ks*32 + lk];
            #pragma unroll
            for (int mi = 0; mi < 2; mi++) {
                racc[mi] = mfma16x16x32(sqf[mi*4 + ks], bm, racc[mi]);
                yacc[mi] = mfma16x16x32(skf[mi*4 + ks], bm, yacc[mi]);
            }
        }
        if (n < NSEG - 1) loadraw(n + 1, nxtq, nxtk);
        #pragma unroll
        for (int mi = 0; mi < 2; mi++)
            #pragma unroll
            for (int j = 0; j < 4; j++)
                yT[l15*136 + w*32 + mi*16 + r0 + j] = (bf16)(yacc[mi][j] * ivk[mi][j]);
        __syncthreads();
        f32x4 zacc[2];
        #pragma unroll
        for (int mi = 0; mi < 2; mi++)
            #pragma unroll
            for (int e = 0; e < 4; e++) zacc[mi][e] = 0.f;
        #pragma unroll
        for (int ks = 0; ks < 4; ks++) {
            bf16x8 bz = *(const bf16x8*)&yT[l15*136 + ks*32 + lk];
            #pragma unroll
            for (int mi = 0; mi < 2; mi++) {
                bf16x8 az = *(const bf16x8*)&skT[(w*32 + mi*16 + l15)*136 + ks*32 + lk];
                zacc[mi] = mfma16x16x32(az, bz, zacc[mi]);
            }
        }
        #pragma unroll
        for (int mi = 0; mi < 2; mi++)
            #pragma unroll
            for (int j = 0; j < 4; j++) {
                const int sx = w*32 + mi*16 + r0 + j;
                const float rv = racc[mi][j] / dqv[mi][j];
                lob[((size_t)(n*SEGLEN + sx)*NBATCH + b)*DMODEL + h*DHEAD + cdv] =
                    (bf16)(lv[mi][j] + g * rv);
                mast[mi][j] += uval[mi][j] - zacc[mi][j];
                memT[l15*136 + sx] = (bf16)mast[mi][j];
            }
        __syncthreads();
    };

    loadraw(1, qA, kA);
    for (int n = 1; n < NSEG; n += 2) {
        step(n, qA, kA, qB, kB);
        if (n + 1 < NSEG) step(n + 1, qB, kB, qA, kA);
    }
}

// ---------------------------------------------------------------------------
// Workspace layout (max 295,698,432 B, proven-safe):
//   [0)            qkvb  157,286,400
//   [157,286,400)  lob    52,428,800
//   [209,715,200)  woT     8,388,608
//   [218,103,808)  abf    52,428,800   -> reused as Ub (bf16) after QKV GEMM
//   [270,532,608)  wqkvT  25,165,824   -> reused as ksum/normp/denqb/invkb
// ---------------------------------------------------------------------------
extern "C" void kernel_launch(void* const* d_in, const int* in_sizes, int n_in,
                              void* d_out, int out_size, void* d_ws, size_t ws_size,
                              hipStream_t stream)
{
    (void)in_sizes; (void)n_in; (void)out_size; (void)ws_size;
    const float* hidden = (const float*)d_in[0];
    const float* w_qkv  = (const float*)d_in[2];
    const float* w_o    = (const float*)d_in[3];
    const float* bal    = (const float*)d_in[4];

    char* ws = (char*)d_ws;
    bf16*  qkvb  = (bf16*)ws;
    bf16*  lob   = (bf16*)(ws + 157286400);
    bf16*  woT   = (bf16*)(ws + 209715200);
    bf16*  abf   = (bf16*)(ws + 218103808);
    bf16*  Ub    = abf;
    bf16*  wqkvT = (bf16*)(ws + 270532608);
    float* ksum  = (float*)(ws + 270532608);
    float* normp = (float*)(ws + 271351808);
    float* denqb = (float*)(ws + 272171008);
    float* invkb = (float*)(ws + 272990208);

    dim3 blk(256);
    f32_to_bf16_vec<<<2048, blk, 0, stream>>>(hidden, abf, MROWS*DMODEL/8);
    transpose_f32_to_bf16<<<dim3(QKV_N/32, DMODEL/32), blk, 0, stream>>>(w_qkv, wqkvT, DMODEL, QKV_N);
    transpose_f32_to_bf16<<<dim3(DMODEL/32, DMODEL/32), blk, 0, stream>>>(w_o, woT, DMODEL, DMODEL);

    gemm256<true><<<dim3(MROWS/256, QKV_N/256), 512, 0, stream>>>(abf, wqkvT, qkvb, QKV_N);

    prep_ksum<<<dim3(NSEG, 32), blk, 0, stream>>>(qkvb, ksum);
    prefix_norm<<<32, 128, 0, stream>>>(ksum, normp);
    prep_U<<<dim3(NSEG, 32), blk, 0, stream>>>(qkvb, normp, Ub, denqb, invkb);

    attn_local<<<dim3(NSEG*NBATCH*NHEADS), blk, 0, stream>>>(qkvb, lob, bal);
    scan2<<<256, blk, 0, stream>>>(qkvb, Ub, denqb, invkb, lob, bal);

    gemm256<false><<<dim3(MROWS/256, DMODEL/256), 512, 0, stream>>>(lob, woT, d_out, DMODEL);
}